// Round 1
// baseline (485.594 us; speedup 1.0000x reference)
//
#include <hip/hip_runtime.h>
#include <cstdint>
#include <cstddef>

#define HW    32768     // 128*256 feature pixels per image
#define NCLS  19
#define VIEWS 50
#define NT    38        // 2 images * 19 classes
#define NR    1900      // NT * VIEWS anchor rows
#define CH    256       // channels

// ---- workspace layout (4-byte elements) ----
#define OFF_RAND 0u        // float [2][HW]
#define OFF_LD   65536u    // int   [2][HW]
#define OFF_SEL  131072u   // int   [NT][VIEWS]
#define OFF_FCF  133120u   // float [NR][CH]
#define OFF_FOF  619520u   // float [NR][CH]
#define OFF_NEG  1105920u  // float [3][NR]
#define OFF_POS  1111680u  // float [3][NR][100]
// total 1681680 elems = 6.73 MB

__device__ __forceinline__ unsigned rotl32(unsigned x, int d) {
    return (x << d) | (x >> (32 - d));
}

// Kernel 1: JAX threefry2x32 uniforms for key(42), shape (2, HW), plus label downsample.
__global__ void prep_kernel(const int* __restrict__ label,
                            float* __restrict__ rnd, int* __restrict__ ld) {
    int j = blockIdx.x * blockDim.x + threadIdx.x;
    if (j >= HW) return;
    // counts = iota(65536); lane j pairs (j, j+HW); key = (0, 42)
    unsigned x0 = (unsigned)j, x1 = (unsigned)(j + HW);
    const unsigned ks0 = 0u, ks1 = 42u, ks2 = 0x1BD11BDAu ^ 0u ^ 42u;
    x0 += ks0; x1 += ks1;
#define TF_RND(r) { x0 += x1; x1 = rotl32(x1, r); x1 ^= x0; }
    TF_RND(13) TF_RND(15) TF_RND(26) TF_RND(6)   x0 += ks1; x1 += ks2 + 1u;
    TF_RND(17) TF_RND(29) TF_RND(16) TF_RND(24)  x0 += ks2; x1 += ks0 + 2u;
    TF_RND(13) TF_RND(15) TF_RND(26) TF_RND(6)   x0 += ks0; x1 += ks1 + 3u;
    TF_RND(17) TF_RND(29) TF_RND(16) TF_RND(24)  x0 += ks1; x1 += ks2 + 4u;
    TF_RND(13) TF_RND(15) TF_RND(26) TF_RND(6)   x0 += ks2; x1 += ks0 + 5u;
#undef TF_RND
    rnd[j]      = __uint_as_float((x0 >> 9) | 0x3f800000u) - 1.0f;
    rnd[HW + j] = __uint_as_float((x1 >> 9) | 0x3f800000u) - 1.0f;
    // nearest-neighbour downsample: label[n, 4y, 4x], label is (2,512,1024)
    int y = j >> 8, x = j & 255;
    int off = (y << 2) * 1024 + (x << 2);
    ld[j]      = label[off];
    ld[HW + j] = label[512 * 1024 + off];
}

// Kernel 2: per (image, class) select the 50 smallest (rand, idx) keys among class pixels.
#define CAP 3072
__global__ void select_kernel(const float* __restrict__ rnd,
                              const int* __restrict__ ld, int* __restrict__ sel) {
    int t = blockIdx.x;             // 0..37
    int n = t / NCLS, c = t % NCLS;
    __shared__ int s_count;
    __shared__ unsigned long long s_key[CAP];
    __shared__ unsigned long long s_red[256];
    int tid = threadIdx.x;
    if (tid == 0) s_count = 0;
    __syncthreads();
    const int*   ldn = ld + n * HW;
    const float* rn  = rnd + n * HW;
    for (int j = tid; j < HW; j += 256) {
        if (ldn[j] == c) {
            int p = atomicAdd(&s_count, 1);
            if (p < CAP)
                s_key[p] = (((unsigned long long)__float_as_uint(rn[j])) << 32) | (unsigned)j;
        }
    }
    __syncthreads();
    int count = min(s_count, CAP);
    for (int v = 0; v < VIEWS; ++v) {
        unsigned long long best = ~0ull;
        for (int p = tid; p < count; p += 256) {
            unsigned long long k = s_key[p];
            if (k < best) best = k;
        }
        s_red[tid] = best;
        __syncthreads();
        for (int s = 128; s > 0; s >>= 1) {
            if (tid < s) {
                unsigned long long o = s_red[tid + s];
                if (o < s_red[tid]) s_red[tid] = o;
            }
            __syncthreads();
        }
        unsigned long long winner = s_red[0];
        if (tid == 0)
            sel[t * VIEWS + v] = (winner == ~0ull) ? -1 : (int)(winner & 0xffffffffu);
        if (winner != ~0ull)
            for (int p = tid; p < count; p += 256)
                if (s_key[p] == winner) s_key[p] = ~0ull;
        __syncthreads();
    }
    // (practically unreachable) class has < VIEWS pixels: stable argsort puts
    // non-class pixels (key 2.0) next, in index order.
    if (tid == 0 && count < VIEWS) {
        int fill = count < 0 ? 0 : count;
        for (int j = 0; j < HW && fill < VIEWS; ++j)
            if (ldn[j] != c) sel[t * VIEWS + fill++] = j;
    }
}

// Kernel 3: gather sampled pixels and l2-normalize over channels.
__global__ void gather_kernel(const float* __restrict__ cf, const float* __restrict__ of,
                              const int* __restrict__ sel,
                              float* __restrict__ fcf, float* __restrict__ fof) {
    int r = blockIdx.x;              // 0..1899, r = t*VIEWS + v
    int t = r / VIEWS, v = r % VIEWS;
    int n = t / NCLS;
    int idx = sel[t * VIEWS + v];
    int ch = threadIdx.x;
    float vc = cf[(size_t)(n * CH + ch) * HW + idx];
    float vo = of[(size_t)(n * CH + ch) * HW + idx];
    __shared__ float sc[256], so[256];
    sc[ch] = vc * vc; so[ch] = vo * vo;
    __syncthreads();
    for (int s = 128; s > 0; s >>= 1) {
        if (ch < s) { sc[ch] += sc[ch + s]; so[ch] += so[ch + s]; }
        __syncthreads();
    }
    float nc = fmaxf(sqrtf(sc[0]), 1e-12f);
    float no = fmaxf(sqrtf(so[0]), 1e-12f);
    fcf[r * CH + ch] = vc / nc;
    fof[r * CH + ch] = vo / no;
}

// Kernel 4: tiled fp32 Gram (A.B^T * 10) with fused InfoNCE epilogue.
// z=0: cm (fcf,fof); z=1: vis (fcf,fcf); z=2: aux (fof,fof). TEMP==CM_TEMP==0.1.
#define TI 64
#define TJ 64
#define LDP 20   // padded leading dim (floats); 80B rows keep float4 alignment
__global__ __launch_bounds__(256) void gram_kernel(const float* __restrict__ fcf,
                                                   const float* __restrict__ fof,
                                                   float* __restrict__ negsum,
                                                   float* __restrict__ posdot) {
    int z = blockIdx.z;
    const float* A = (z == 2) ? fof : fcf;
    const float* B = (z == 1) ? fcf : fof;
    int i0 = blockIdx.y * TI, j0 = blockIdx.x * TJ;
    int tid = threadIdx.x;
    int tx = tid & 15, ty = tid >> 4;
    __shared__ float As[TI][LDP], Bs[TJ][LDP];
    __shared__ float negs[TI];
    float acc[4][4] = {};
    for (int kc = 0; kc < CH; kc += 16) {
        for (int m = 0; m < 4; ++m) {
            int e = tid + m * 256;
            int row = e >> 4, kk = e & 15;
            int gi = i0 + row, gj = j0 + row;
            As[row][kk] = (gi < NR) ? A[gi * CH + kc + kk] : 0.0f;
            Bs[row][kk] = (gj < NR) ? B[gj * CH + kc + kk] : 0.0f;
        }
        __syncthreads();
        for (int k4 = 0; k4 < 16; k4 += 4) {
            float4 av[4], bv[4];
            for (int a = 0; a < 4; ++a) av[a] = *(const float4*)&As[ty + 16 * a][k4];
            for (int b = 0; b < 4; ++b) bv[b] = *(const float4*)&Bs[tx + 16 * b][k4];
            for (int a = 0; a < 4; ++a)
                for (int b = 0; b < 4; ++b)
                    acc[a][b] += av[a].x * bv[b].x + av[a].y * bv[b].y +
                                 av[a].z * bv[b].z + av[a].w * bv[b].w;
        }
        __syncthreads();
    }
    if (tid < TI) negs[tid] = 0.0f;
    __syncthreads();
    float* pd = posdot + (size_t)z * NR * 100;
    for (int a = 0; a < 4; ++a) {
        int i = i0 + ty + 16 * a;
        if (i >= NR) continue;
        int ci = (i / VIEWS) % NCLS;
        float negacc = 0.0f;
        for (int b = 0; b < 4; ++b) {
            int j = j0 + tx + 16 * b;
            if (j >= NR) continue;
            int cj = (j / VIEWS) % NCLS;
            float d = acc[a][b] * 10.0f;   // 1/temp
            if (ci == cj) {
                int p = (j / (NCLS * VIEWS)) * VIEWS + (j % VIEWS);  // slot 0..99
                pd[(size_t)i * 100 + p] = d;
            } else {
                negacc += __expf(d);
            }
        }
        atomicAdd(&negs[ty + 16 * a], negacc);
    }
    __syncthreads();
    if (tid < TI) {
        int i = i0 + tid;
        if (i < NR && negs[tid] != 0.0f)
            atomicAdd(&negsum[z * NR + i], negs[tid]);
    }
}

// Kernel 5: per-anchor InfoNCE from stored same-class dots + neg exp sums.
__global__ void finalize_kernel(const float* __restrict__ negsum,
                                const float* __restrict__ posdot,
                                float* __restrict__ out) {
    int g = blockIdx.x * 256 + threadIdx.x;
    __shared__ float part[3];
    if (threadIdx.x < 3) part[threadIdx.x] = 0.0f;
    __syncthreads();
    if (g < 3 * NR) {
        int l = g / NR, i = g % NR;
        float NL = negsum[l * NR + i];
        int pself = (i / (NCLS * VIEWS)) * VIEWS + (i % VIEWS);
        const float* pd = posdot + ((size_t)l * NR + i) * 100;
        float s = 0.0f;
        for (int p = 0; p < 100; ++p) {
            if (p == pself) continue;
            float d = pd[p];
            s += d - logf(__expf(d) + NL);
        }
        atomicAdd(&part[l], s);
    }
    __syncthreads();
    if (threadIdx.x < 3)
        atomicAdd(&out[threadIdx.x], -part[threadIdx.x] * (1.0f / (99.0f * 1900.0f)));
}

extern "C" void kernel_launch(void* const* d_in, const int* in_sizes, int n_in,
                              void* d_out, int out_size, void* d_ws, size_t ws_size,
                              hipStream_t stream) {
    (void)in_sizes; (void)n_in; (void)out_size; (void)ws_size;
    const int*   label = (const int*)d_in[0];
    const float* cf    = (const float*)d_in[1];
    const float* of    = (const float*)d_in[2];
    float* ws     = (float*)d_ws;
    float* rnd    = ws + OFF_RAND;
    int*   ld     = (int*)(ws + OFF_LD);
    int*   sel    = (int*)(ws + OFF_SEL);
    float* fcf    = ws + OFF_FCF;
    float* fof    = ws + OFF_FOF;
    float* negsum = ws + OFF_NEG;
    float* posdot = ws + OFF_POS;
    float* out    = (float*)d_out;

    hipMemsetAsync(negsum, 0, 3 * NR * sizeof(float), stream);
    hipMemsetAsync(out, 0, 3 * sizeof(float), stream);

    prep_kernel<<<HW / 256, 256, 0, stream>>>(label, rnd, ld);
    select_kernel<<<NT, 256, 0, stream>>>(rnd, ld, sel);
    gather_kernel<<<NR, 256, 0, stream>>>(cf, of, sel, fcf, fof);
    dim3 g4((NR + TJ - 1) / TJ, (NR + TI - 1) / TI, 3);
    gram_kernel<<<g4, 256, 0, stream>>>(fcf, fof, negsum, posdot);
    finalize_kernel<<<(3 * NR + 255) / 256, 256, 0, stream>>>(negsum, posdot, out);
}

// Round 3
// 306.359 us; speedup vs baseline: 1.5850x; 1.5850x over previous
//
#include <hip/hip_runtime.h>
#include <hip/hip_bf16.h>
#include <cstdint>
#include <cstddef>

#define HW    32768     // 128*256 feature pixels per image
#define NCLS  19
#define VIEWS 50
#define NT    38        // 2 images * 19 classes
#define NR    1900      // NT * VIEWS anchor rows
#define NRP   1920      // padded to 30*64 tiles
#define CH    256       // channels

// ---- workspace layout (FLOAT units; fcf/fof are ushort arrays = count/2 floats) ----
#define OFF_RAND 0u        // float  [2][HW]                         (65536)
#define OFF_LD   65536u    // int    [2][HW]                         (65536)
#define OFF_SEL  131072u   // int    [NT*VIEWS]=1900                 (pad to 2048)
#define OFF_FCF  133120u   // ushort [NRP][CH] = 491520 us = 245760 f
#define OFF_FOF  378880u   // ushort [NRP][CH] = 245760 f
#define OFF_NEG  624640u   // float  [3][NR] = 5700                  (pad to 5760)
#define OFF_POS  630400u   // float  [3][NR][100] = 570000
// end 1200400 floats = 4.80 MB

typedef __attribute__((ext_vector_type(8))) short short8;
typedef __attribute__((ext_vector_type(4))) float f32x4;

__device__ __forceinline__ unsigned rotl32(unsigned x, int d) {
    return (x << d) | (x >> (32 - d));
}

__device__ __forceinline__ void async_copy16(const void* g, void* l) {
    __builtin_amdgcn_global_load_lds(
        (const __attribute__((address_space(1))) unsigned int*)g,
        (__attribute__((address_space(3))) unsigned int*)l, 16, 0, 0);
}

// Kernel 1: JAX threefry2x32 uniforms for key(42), shape (2, HW), plus label downsample.
__global__ void prep_kernel(const int* __restrict__ label,
                            float* __restrict__ rnd, int* __restrict__ ld) {
    int j = blockIdx.x * blockDim.x + threadIdx.x;
    if (j >= HW) return;
    unsigned x0 = (unsigned)j, x1 = (unsigned)(j + HW);
    const unsigned ks0 = 0u, ks1 = 42u, ks2 = 0x1BD11BDAu ^ 0u ^ 42u;
    x0 += ks0; x1 += ks1;
#define TF_RND(r) { x0 += x1; x1 = rotl32(x1, r); x1 ^= x0; }
    TF_RND(13) TF_RND(15) TF_RND(26) TF_RND(6)   x0 += ks1; x1 += ks2 + 1u;
    TF_RND(17) TF_RND(29) TF_RND(16) TF_RND(24)  x0 += ks2; x1 += ks0 + 2u;
    TF_RND(13) TF_RND(15) TF_RND(26) TF_RND(6)   x0 += ks0; x1 += ks1 + 3u;
    TF_RND(17) TF_RND(29) TF_RND(16) TF_RND(24)  x0 += ks1; x1 += ks2 + 4u;
    TF_RND(13) TF_RND(15) TF_RND(26) TF_RND(6)   x0 += ks2; x1 += ks0 + 5u;
#undef TF_RND
    rnd[j]      = __uint_as_float((x0 >> 9) | 0x3f800000u) - 1.0f;
    rnd[HW + j] = __uint_as_float((x1 >> 9) | 0x3f800000u) - 1.0f;
    int y = j >> 8, x = j & 255;
    int off = (y << 2) * 1024 + (x << 2);
    ld[j]      = label[off];
    ld[HW + j] = label[512 * 1024 + off];
}

// Kernel 2: per (image, class) the 50 smallest (rand, idx) keys among class pixels.
// Keys held in registers; shuffle-based argmin (2 barriers/pass).
#define CAP 3072
#define KPT 12   // ceil(CAP/256)
__global__ __launch_bounds__(256) void select_kernel(const float* __restrict__ rnd,
                                                     const int* __restrict__ ld,
                                                     int* __restrict__ sel) {
    int t = blockIdx.x, n = t / NCLS, c = t % NCLS;
    __shared__ int s_count;
    __shared__ unsigned long long s_key[CAP];
    __shared__ unsigned long long s_wmin[4];
    int tid = threadIdx.x;
    if (tid == 0) s_count = 0;
    __syncthreads();
    const int*   ldn = ld + n * HW;
    const float* rn  = rnd + n * HW;
    const int4*  ld4 = (const int4*)ldn;
    for (int k = tid; k < HW / 4; k += 256) {
        int4 v = ld4[k];
        int j = k * 4;
#define PUSH(val, jj) if ((val) == c) { int p = atomicAdd(&s_count, 1); \
        if (p < CAP) s_key[p] = (((unsigned long long)__float_as_uint(rn[jj])) << 32) | (unsigned)(jj); }
        PUSH(v.x, j) PUSH(v.y, j + 1) PUSH(v.z, j + 2) PUSH(v.w, j + 3)
#undef PUSH
    }
    __syncthreads();
    int count = min(s_count, CAP);
    unsigned long long key[KPT];
    int nk = 0;
    for (int p = tid; p < count; p += 256) key[nk++] = s_key[p];
    int wave = tid >> 6, lane = tid & 63;
    for (int v = 0; v < VIEWS; ++v) {
        unsigned long long best = ~0ull;
        for (int q = 0; q < nk; ++q) best = (key[q] < best) ? key[q] : best;
        for (int m = 32; m >= 1; m >>= 1) {
            unsigned long long o = __shfl_xor(best, m);
            if (o < best) best = o;
        }
        if (lane == 0) s_wmin[wave] = best;
        __syncthreads();
        unsigned long long w01 = (s_wmin[0] < s_wmin[1]) ? s_wmin[0] : s_wmin[1];
        unsigned long long w23 = (s_wmin[2] < s_wmin[3]) ? s_wmin[2] : s_wmin[3];
        unsigned long long winner = (w01 < w23) ? w01 : w23;
        if (tid == 0)
            sel[t * VIEWS + v] = (winner == ~0ull) ? 0 : (int)(winner & 0xffffffffu);
        for (int q = 0; q < nk; ++q) if (key[q] == winner) key[q] = ~0ull;
        __syncthreads();   // protect s_wmin before next pass overwrites
    }
}

// Kernel 3: gather sampled pixels, l2-normalize over channels, store bf16 bits.
__global__ __launch_bounds__(256) void gather_kernel(const float* __restrict__ cf,
                                                     const float* __restrict__ of,
                                                     const int* __restrict__ sel,
                                                     unsigned short* __restrict__ fcf,
                                                     unsigned short* __restrict__ fof) {
    int r = blockIdx.x;              // 0..1899
    int t = r / VIEWS;
    int n = t / NCLS;
    int idx = sel[r];
    int ch = threadIdx.x;
    float vc = cf[(size_t)(n * CH + ch) * HW + idx];
    float vo = of[(size_t)(n * CH + ch) * HW + idx];
    __shared__ float partc[4], parto[4];
    float sc = vc * vc, so = vo * vo;
    for (int m = 32; m >= 1; m >>= 1) {
        sc += __shfl_xor(sc, m);
        so += __shfl_xor(so, m);
    }
    int wave = ch >> 6, lane = ch & 63;
    if (lane == 0) { partc[wave] = sc; parto[wave] = so; }
    __syncthreads();
    float nc = fmaxf(sqrtf(partc[0] + partc[1] + partc[2] + partc[3]), 1e-12f);
    float no = fmaxf(sqrtf(parto[0] + parto[1] + parto[2] + parto[3]), 1e-12f);
    __hip_bfloat16 hc = __float2bfloat16(vc / nc);
    __hip_bfloat16 ho = __float2bfloat16(vo / no);
    fcf[r * CH + ch] = *(unsigned short*)&hc;
    fof[r * CH + ch] = *(unsigned short*)&ho;
}

// Kernel 4: bf16 MFMA Gram (A.B^T * 10) with fused InfoNCE epilogue.
// z=0: cm (fcf,fof); z=1: vis (fcf,fcf); z=2: aux (fof,fof).
__global__ __launch_bounds__(256) void gram_kernel(const unsigned short* __restrict__ fcf,
                                                   const unsigned short* __restrict__ fof,
                                                   float* __restrict__ negsum,
                                                   float* __restrict__ posdot) {
    int z = blockIdx.z;
    const unsigned short* A = (z == 2) ? fof : fcf;
    const unsigned short* B = (z == 1) ? fcf : fof;
    int i0 = blockIdx.y * 64, j0 = blockIdx.x * 64;
    int tid = threadIdx.x;
    int wave = tid >> 6, lane = tid & 63;
    __shared__ unsigned short As[64][32], Bs[64][32];
    __shared__ float negs[64];
    if (tid < 64) negs[tid] = 0.0f;
    f32x4 acc[4] = {{0,0,0,0},{0,0,0,0},{0,0,0,0},{0,0,0,0}};
    // staging: lane l of wave w fills LDS bytes base(w*16 rows) + l*16
    int srow = wave * 16 + (lane >> 2);
    int scol = (lane & 3) * 8;
    const unsigned short* ga = A + (size_t)(i0 + srow) * CH + scol;   // rows padded to NRP
    const unsigned short* gb = B + (size_t)(j0 + srow) * CH + scol;
    unsigned short* la = &As[wave * 16][0];
    unsigned short* lb = &Bs[wave * 16][0];
    int arow = wave * 16 + (lane & 15);
    int koff = (lane >> 4) * 8;
    for (int kc = 0; kc < CH; kc += 32) {
        async_copy16(ga + kc, la);
        async_copy16(gb + kc, lb);
        __syncthreads();
        short8 af = *(const short8*)&As[arow][koff];
        for (int b = 0; b < 4; ++b) {
            short8 bf = *(const short8*)&Bs[b * 16 + (lane & 15)][koff];
            acc[b] = __builtin_amdgcn_mfma_f32_16x16x32_bf16(af, bf, acc[b], 0, 0, 0);
        }
        __syncthreads();
    }
    // epilogue: C/D layout col=lane&15, row=(lane>>4)*4+reg  (this wave's rows: +wave*16)
    float* pd = posdot + (size_t)z * NR * 100;
    int col = lane & 15, quad = lane >> 4;
    for (int r = 0; r < 4; ++r) {
        int irow = wave * 16 + quad * 4 + r;
        int i = i0 + irow;
        bool iok = (i < NR);
        int ci = (i / VIEWS) % NCLS;
        float negacc = 0.0f;
        for (int b = 0; b < 4; ++b) {
            int j = j0 + b * 16 + col;
            if (!iok || j >= NR) continue;
            int cj = (j / VIEWS) % NCLS;
            float d = acc[b][r] * 10.0f;   // 1/temp
            if (ci == cj) {
                int p = (j / (NCLS * VIEWS)) * VIEWS + (j % VIEWS);  // slot 0..99
                pd[(size_t)i * 100 + p] = d;
            } else {
                negacc += __expf(d);
            }
        }
        for (int m = 8; m >= 1; m >>= 1) negacc += __shfl_xor(negacc, m);
        if (col == 0 && iok) negs[irow] = negacc;   // unique writer per row
    }
    __syncthreads();
    if (tid < 64) {
        int i = i0 + tid;
        if (i < NR) atomicAdd(&negsum[z * NR + i], negs[tid]);
    }
}

// Kernel 5: per-anchor InfoNCE from stored same-class dots + neg exp sums.
__global__ void finalize_kernel(const float* __restrict__ negsum,
                                const float* __restrict__ posdot,
                                float* __restrict__ out) {
    int g = blockIdx.x * 256 + threadIdx.x;
    __shared__ float part[3];
    if (threadIdx.x < 3) part[threadIdx.x] = 0.0f;
    __syncthreads();
    if (g < 3 * NR) {
        int l = g / NR, i = g % NR;
        float NL = negsum[l * NR + i];
        int pself = (i / (NCLS * VIEWS)) * VIEWS + (i % VIEWS);
        const float* pd = posdot + ((size_t)l * NR + i) * 100;
        float s = 0.0f;
        for (int p = 0; p < 100; ++p) {
            if (p == pself) continue;
            float d = pd[p];
            s += d - logf(__expf(d) + NL);
        }
        atomicAdd(&part[l], s);
    }
    __syncthreads();
    if (threadIdx.x < 3)
        atomicAdd(&out[threadIdx.x], -part[threadIdx.x] * (1.0f / (99.0f * 1900.0f)));
}

extern "C" void kernel_launch(void* const* d_in, const int* in_sizes, int n_in,
                              void* d_out, int out_size, void* d_ws, size_t ws_size,
                              hipStream_t stream) {
    (void)in_sizes; (void)n_in; (void)out_size; (void)ws_size;
    const int*   label = (const int*)d_in[0];
    const float* cf    = (const float*)d_in[1];
    const float* of    = (const float*)d_in[2];
    float* ws = (float*)d_ws;
    float*          rnd    = ws + OFF_RAND;
    int*            ld     = (int*)(ws + OFF_LD);
    int*            sel    = (int*)(ws + OFF_SEL);
    unsigned short* fcf    = (unsigned short*)(ws + OFF_FCF);
    unsigned short* fof    = (unsigned short*)(ws + OFF_FOF);
    float*          negsum = ws + OFF_NEG;
    float*          posdot = ws + OFF_POS;
    float*          out    = (float*)d_out;

    hipMemsetAsync(negsum, 0, 3 * NR * sizeof(float), stream);
    hipMemsetAsync(out, 0, 3 * sizeof(float), stream);
    // zero bf16 pad rows 1900..1919 of both feature matrices
    hipMemsetAsync(fcf + (size_t)NR * CH, 0, (size_t)(NRP - NR) * CH * sizeof(unsigned short), stream);
    hipMemsetAsync(fof + (size_t)NR * CH, 0, (size_t)(NRP - NR) * CH * sizeof(unsigned short), stream);

    prep_kernel<<<HW / 256, 256, 0, stream>>>(label, rnd, ld);
    select_kernel<<<NT, 256, 0, stream>>>(rnd, ld, sel);
    gather_kernel<<<NR, 256, 0, stream>>>(cf, of, sel, fcf, fof);
    dim3 g4(NRP / 64, NRP / 64, 3);
    gram_kernel<<<g4, 256, 0, stream>>>(fcf, fof, negsum, posdot);
    finalize_kernel<<<(3 * NR + 255) / 256, 256, 0, stream>>>(negsum, posdot, out);
}

// Round 4
// 208.488 us; speedup vs baseline: 2.3291x; 1.4694x over previous
//
#include <hip/hip_runtime.h>
#include <hip/hip_bf16.h>
#include <cstdint>
#include <cstddef>

#define HW    32768     // 128*256 feature pixels per image
#define NCLS  19
#define VIEWS 50
#define NT    38        // 2 images * 19 classes
#define NR    1900      // NT * VIEWS anchor rows
#define NRP   1920      // padded to 30*64 tiles
#define CH    256       // channels
#define CAP   3072      // max keys kept per (image,class) list (mean ~1724, sd ~41)

// ---- workspace layout (FLOAT units) ----
#define OFF_RAND 0u        // float [2][HW]                     65536
#define OFF_LD   65536u    // int   [2][HW]                     65536
#define OFF_SEL  131072u   // int   [NT*VIEWS]=1900 (pad 2048)
#define OFF_CNT  133120u   // int   [NT] (pad 64)
#define OFF_KEYS 133184u   // ull   [NT][CAP] = 233472 floats (8B-aligned: 133184*4 % 8 == 0)
#define OFF_FCF  366656u   // ushort[NRP][CH] = 245760 floats
#define OFF_FOF  612416u   // ushort[NRP][CH] = 245760 floats
#define OFF_NEG  858176u   // float [3][NR] = 5700 (pad 5760)
#define OFF_POS  863936u   // float [3][NR][100] = 570000
// end 1433936 floats = 5.74 MB

typedef __attribute__((ext_vector_type(8))) short short8;
typedef __attribute__((ext_vector_type(4))) float f32x4;

__device__ __forceinline__ unsigned rotl32(unsigned x, int d) {
    return (x << d) | (x >> (32 - d));
}

__device__ __forceinline__ void async_copy16(const void* g, void* l) {
    __builtin_amdgcn_global_load_lds(
        (const __attribute__((address_space(1))) unsigned int*)g,
        (__attribute__((address_space(3))) unsigned int*)l, 16, 0, 0);
}

// Kernel 1: threefry2x32 uniforms (key 42) + label downsample + per-(n,c) key
// compaction into global lists (block-aggregated range reservation) + negsum zero.
__global__ __launch_bounds__(256) void prep_kernel(const int* __restrict__ label,
                                                   float* __restrict__ rnd,
                                                   int* __restrict__ ld,
                                                   int* __restrict__ counts,
                                                   unsigned long long* __restrict__ keys,
                                                   float* __restrict__ negsum) {
    int tid = threadIdx.x;
    int j = blockIdx.x * 256 + tid;
    // threefry2x32: counts iota(65536), lane j pairs (j, j+HW), key (0,42)
    unsigned x0 = (unsigned)j, x1 = (unsigned)(j + HW);
    const unsigned ks0 = 0u, ks1 = 42u, ks2 = 0x1BD11BDAu ^ 0u ^ 42u;
    x0 += ks0; x1 += ks1;
#define TF_RND(r) { x0 += x1; x1 = rotl32(x1, r); x1 ^= x0; }
    TF_RND(13) TF_RND(15) TF_RND(26) TF_RND(6)   x0 += ks1; x1 += ks2 + 1u;
    TF_RND(17) TF_RND(29) TF_RND(16) TF_RND(24)  x0 += ks2; x1 += ks0 + 2u;
    TF_RND(13) TF_RND(15) TF_RND(26) TF_RND(6)   x0 += ks0; x1 += ks1 + 3u;
    TF_RND(17) TF_RND(29) TF_RND(16) TF_RND(24)  x0 += ks1; x1 += ks2 + 4u;
    TF_RND(13) TF_RND(15) TF_RND(26) TF_RND(6)   x0 += ks2; x1 += ks0 + 5u;
#undef TF_RND
    float r0 = __uint_as_float((x0 >> 9) | 0x3f800000u) - 1.0f;
    float r1 = __uint_as_float((x1 >> 9) | 0x3f800000u) - 1.0f;
    rnd[j]      = r0;
    rnd[HW + j] = r1;
    int y = j >> 8, x = j & 255;
    int off = (y << 2) * 1024 + (x << 2);
    int c0 = label[off];
    int c1 = label[512 * 1024 + off];
    ld[j]      = c0;
    ld[HW + j] = c1;
    if (j < 3 * NR) negsum[j] = 0.0f;

    // block-aggregated push into per-(n,c) lists
    __shared__ int lcnt[NT], lbase[NT];
    if (tid < NT) lcnt[tid] = 0;
    __syncthreads();
    int t0 = c0, t1 = NCLS + c1;
    int p0 = atomicAdd(&lcnt[t0], 1);
    int p1 = atomicAdd(&lcnt[t1], 1);
    __syncthreads();
    if (tid < NT) {
        int c = lcnt[tid];
        lbase[tid] = (c > 0) ? atomicAdd(&counts[tid], c) : 0;
    }
    __syncthreads();
    int s0 = lbase[t0] + p0;
    int s1 = lbase[t1] + p1;
    if (s0 < CAP)
        keys[(size_t)t0 * CAP + s0] = (((unsigned long long)__float_as_uint(r0)) << 32) | (unsigned)j;
    if (s1 < CAP)
        keys[(size_t)t1 * CAP + s1] = (((unsigned long long)__float_as_uint(r1)) << 32) | (unsigned)j;
}

// Kernel 2: exact order-free top-50 per (image,class) via 256-bin histogram select.
// Keys f = m/2^23 (m 23-bit int) -> bin = (f*2^23) >> 15 is exact & monotone; full
// 64-bit (float_bits, idx) keys resolve the boundary bin and ties.
__global__ __launch_bounds__(256) void select_kernel(const int* __restrict__ counts,
                                                     const unsigned long long* __restrict__ keys,
                                                     const int* __restrict__ ld,
                                                     int* __restrict__ sel) {
    int t = blockIdx.x;
    int tid = threadIdx.x;
    int cnt = min(counts[t], CAP);
    const unsigned long long* g = keys + (size_t)t * CAP;
    __shared__ unsigned hist[256];
    __shared__ unsigned long long cand[256];
    __shared__ int s_B, s_nbelow, s_ncand;
    hist[tid] = 0;
    if (tid == 0) { s_B = 256; s_nbelow = 0; s_ncand = 0; }
    __syncthreads();

    unsigned long long kreg[12];
    int binreg[12];
    int nk = 0;
    for (int p = tid; p < cnt; p += 256) {
        unsigned long long k = g[p];
        unsigned v = (unsigned)(__uint_as_float((unsigned)(k >> 32)) * 8388608.0f);
        int b = (int)(v >> 15);
        kreg[nk] = k; binreg[nk] = b; nk++;
        atomicAdd(&hist[b], 1u);
    }
    __syncthreads();

    if (cnt >= VIEWS) {
        // inclusive Hillis-Steele prefix over 256 bins
        for (int s = 1; s < 256; s <<= 1) {
            unsigned add = (tid >= s) ? hist[tid - s] : 0u;
            unsigned cur = hist[tid];
            __syncthreads();
            hist[tid] = cur + add;
            __syncthreads();
        }
        unsigned cum  = hist[tid];
        unsigned prev = (tid > 0) ? hist[tid - 1] : 0u;
        if (cum >= VIEWS && prev < VIEWS) s_B = tid;   // unique writer
        __syncthreads();
        int B = s_B;
        // classify: bins < B selected outright; bin == B are candidates
        for (int q = 0; q < nk; ++q) {
            if (binreg[q] < B) {
                int pos = atomicAdd(&s_nbelow, 1);
                if (pos < VIEWS) sel[t * VIEWS + pos] = (int)(kreg[q] & 0xffffffffu);
            } else if (binreg[q] == B) {
                int pos = atomicAdd(&s_ncand, 1);
                if (pos < 256) cand[pos] = kreg[q];
            }
        }
        __syncthreads();
        int nbelow = s_nbelow;            // == prefix count below bin B (< 50)
        int need   = VIEWS - nbelow;
        int ncand  = min(s_ncand, 256);
        if (tid < 64) {
            unsigned long long r0 = (tid       < ncand) ? cand[tid]       : ~0ull;
            unsigned long long r1 = (tid + 64  < ncand) ? cand[tid + 64]  : ~0ull;
            unsigned long long r2 = (tid + 128 < ncand) ? cand[tid + 128] : ~0ull;
            unsigned long long r3 = (tid + 192 < ncand) ? cand[tid + 192] : ~0ull;
            for (int v = 0; v < need; ++v) {
                unsigned long long a = (r0 < r1) ? r0 : r1;
                unsigned long long b = (r2 < r3) ? r2 : r3;
                unsigned long long best = (a < b) ? a : b;
                for (int m = 32; m >= 1; m >>= 1) {
                    unsigned long long o = __shfl_xor(best, m);
                    if (o < best) best = o;
                }
                if (tid == 0) sel[t * VIEWS + nbelow + v] = (int)(best & 0xffffffffu);
                if (r0 == best) r0 = ~0ull;
                if (r1 == best) r1 = ~0ull;
                if (r2 == best) r2 = ~0ull;
                if (r3 == best) r3 = ~0ull;
            }
        }
    } else {
        // degenerate class (<50 pixels) — never hit for this input; exact anyway:
        // take all class pixels, then non-class pixels in index order (key 2.0 stable sort).
        for (int q = 0; q < nk; ++q) {
            int pos = atomicAdd(&s_nbelow, 1);
            if (pos < VIEWS) sel[t * VIEWS + pos] = (int)(kreg[q] & 0xffffffffu);
        }
        __syncthreads();
        if (tid == 0) {
            int fill = s_nbelow;
            int n = t / NCLS, c = t % NCLS;
            const int* ldn = ld + n * HW;
            for (int j = 0; j < HW && fill < VIEWS; ++j)
                if (ldn[j] != c) sel[t * VIEWS + fill++] = j;
        }
    }
}

// Kernel 3: gather sampled pixels, l2-normalize, store bf16 bits; pad rows zeroed.
__global__ __launch_bounds__(256) void gather_kernel(const float* __restrict__ cf,
                                                     const float* __restrict__ of,
                                                     const int* __restrict__ sel,
                                                     unsigned short* __restrict__ fcf,
                                                     unsigned short* __restrict__ fof) {
    int r = blockIdx.x;              // 0..NRP-1
    int ch = threadIdx.x;
    if (r >= NR) {                   // zero MFMA pad rows
        fcf[r * CH + ch] = 0;
        fof[r * CH + ch] = 0;
        return;
    }
    int t = r / VIEWS;
    int n = t / NCLS;
    int idx = sel[r];
    float vc = cf[(size_t)(n * CH + ch) * HW + idx];
    float vo = of[(size_t)(n * CH + ch) * HW + idx];
    __shared__ float partc[4], parto[4];
    float sc = vc * vc, so = vo * vo;
    for (int m = 32; m >= 1; m >>= 1) {
        sc += __shfl_xor(sc, m);
        so += __shfl_xor(so, m);
    }
    int wave = ch >> 6, lane = ch & 63;
    if (lane == 0) { partc[wave] = sc; parto[wave] = so; }
    __syncthreads();
    float nc = fmaxf(sqrtf(partc[0] + partc[1] + partc[2] + partc[3]), 1e-12f);
    float no = fmaxf(sqrtf(parto[0] + parto[1] + parto[2] + parto[3]), 1e-12f);
    __hip_bfloat16 hc = __float2bfloat16(vc / nc);
    __hip_bfloat16 ho = __float2bfloat16(vo / no);
    fcf[r * CH + ch] = *(unsigned short*)&hc;
    fof[r * CH + ch] = *(unsigned short*)&ho;
}

// Kernel 4: bf16 MFMA Gram (A.B^T * 10) with fused InfoNCE epilogue.
// z=0: cm (fcf,fof); z=1: vis (fcf,fcf); z=2: aux (fof,fof).
__global__ __launch_bounds__(256) void gram_kernel(const unsigned short* __restrict__ fcf,
                                                   const unsigned short* __restrict__ fof,
                                                   float* __restrict__ negsum,
                                                   float* __restrict__ posdot) {
    int z = blockIdx.z;
    const unsigned short* A = (z == 2) ? fof : fcf;
    const unsigned short* B = (z == 1) ? fcf : fof;
    int i0 = blockIdx.y * 64, j0 = blockIdx.x * 64;
    int tid = threadIdx.x;
    int wave = tid >> 6, lane = tid & 63;
    __shared__ unsigned short As[64][32], Bs[64][32];
    __shared__ float negs[64];
    if (tid < 64) negs[tid] = 0.0f;
    f32x4 acc[4] = {{0,0,0,0},{0,0,0,0},{0,0,0,0},{0,0,0,0}};
    int srow = wave * 16 + (lane >> 2);
    int scol = (lane & 3) * 8;
    const unsigned short* ga = A + (size_t)(i0 + srow) * CH + scol;
    const unsigned short* gb = B + (size_t)(j0 + srow) * CH + scol;
    unsigned short* la = &As[wave * 16][0];
    unsigned short* lb = &Bs[wave * 16][0];
    int arow = wave * 16 + (lane & 15);
    int koff = (lane >> 4) * 8;
    for (int kc = 0; kc < CH; kc += 32) {
        async_copy16(ga + kc, la);
        async_copy16(gb + kc, lb);
        __syncthreads();
        short8 af = *(const short8*)&As[arow][koff];
        for (int b = 0; b < 4; ++b) {
            short8 bf = *(const short8*)&Bs[b * 16 + (lane & 15)][koff];
            acc[b] = __builtin_amdgcn_mfma_f32_16x16x32_bf16(af, bf, acc[b], 0, 0, 0);
        }
        __syncthreads();
    }
    // epilogue: C/D layout col=lane&15, row=(lane>>4)*4+reg (wave's rows: +wave*16)
    float* pd = posdot + (size_t)z * NR * 100;
    int col = lane & 15, quad = lane >> 4;
    for (int r = 0; r < 4; ++r) {
        int irow = wave * 16 + quad * 4 + r;
        int i = i0 + irow;
        bool iok = (i < NR);
        int ci = (i / VIEWS) % NCLS;
        float negacc = 0.0f;
        for (int b = 0; b < 4; ++b) {
            int j = j0 + b * 16 + col;
            if (!iok || j >= NR) continue;
            int cj = (j / VIEWS) % NCLS;
            float d = acc[b][r] * 10.0f;   // 1/temp
            if (ci == cj) {
                int p = (j / (NCLS * VIEWS)) * VIEWS + (j % VIEWS);  // slot 0..99
                pd[(size_t)i * 100 + p] = d;
            } else {
                negacc += __expf(d);
            }
        }
        for (int m = 8; m >= 1; m >>= 1) negacc += __shfl_xor(negacc, m);
        if (col == 0 && iok) negs[irow] = negacc;
    }
    __syncthreads();
    if (tid < 64) {
        int i = i0 + tid;
        if (i < NR) atomicAdd(&negsum[z * NR + i], negs[tid]);
    }
}

// Kernel 5: per-anchor InfoNCE from stored same-class dots + neg exp sums.
__global__ void finalize_kernel(const float* __restrict__ negsum,
                                const float* __restrict__ posdot,
                                float* __restrict__ out) {
    int g = blockIdx.x * 256 + threadIdx.x;
    __shared__ float part[3];
    if (threadIdx.x < 3) part[threadIdx.x] = 0.0f;
    __syncthreads();
    if (g < 3 * NR) {
        int l = g / NR, i = g % NR;
        float NL = negsum[l * NR + i];
        int pself = (i / (NCLS * VIEWS)) * VIEWS + (i % VIEWS);
        const float* pd = posdot + ((size_t)l * NR + i) * 100;
        float s = 0.0f;
        for (int p = 0; p < 100; ++p) {
            if (p == pself) continue;
            float d = pd[p];
            s += d - logf(__expf(d) + NL);
        }
        atomicAdd(&part[l], s);
    }
    __syncthreads();
    if (threadIdx.x < 3)
        atomicAdd(&out[threadIdx.x], -part[threadIdx.x] * (1.0f / (99.0f * 1900.0f)));
}

extern "C" void kernel_launch(void* const* d_in, const int* in_sizes, int n_in,
                              void* d_out, int out_size, void* d_ws, size_t ws_size,
                              hipStream_t stream) {
    (void)in_sizes; (void)n_in; (void)out_size; (void)ws_size;
    const int*   label = (const int*)d_in[0];
    const float* cf    = (const float*)d_in[1];
    const float* of    = (const float*)d_in[2];
    float* ws = (float*)d_ws;
    float*              rnd    = ws + OFF_RAND;
    int*                ld     = (int*)(ws + OFF_LD);
    int*                sel    = (int*)(ws + OFF_SEL);
    int*                counts = (int*)(ws + OFF_CNT);
    unsigned long long* keys   = (unsigned long long*)(ws + OFF_KEYS);
    unsigned short*     fcf    = (unsigned short*)(ws + OFF_FCF);
    unsigned short*     fof    = (unsigned short*)(ws + OFF_FOF);
    float*              negsum = ws + OFF_NEG;
    float*              posdot = ws + OFF_POS;
    float*              out    = (float*)d_out;

    hipMemsetAsync(counts, 0, NT * sizeof(int), stream);
    hipMemsetAsync(out, 0, 3 * sizeof(float), stream);

    prep_kernel<<<HW / 256, 256, 0, stream>>>(label, rnd, ld, counts, keys, negsum);
    select_kernel<<<NT, 256, 0, stream>>>(counts, keys, ld, sel);
    gather_kernel<<<NRP, 256, 0, stream>>>(cf, of, sel, fcf, fof);
    dim3 g4(NRP / 64, NRP / 64, 3);
    gram_kernel<<<g4, 256, 0, stream>>>(fcf, fof, negsum, posdot);
    finalize_kernel<<<(3 * NR + 255) / 256, 256, 0, stream>>>(negsum, posdot, out);
}

// Round 5
// 204.966 us; speedup vs baseline: 2.3691x; 1.0172x over previous
//
#include <hip/hip_runtime.h>
#include <hip/hip_bf16.h>
#include <cstdint>
#include <cstddef>

#define HW    32768     // 128*256 feature pixels per image
#define NCLS  19
#define VIEWS 50
#define NT    38        // 2 images * 19 classes
#define NR    1900      // NT * VIEWS anchor rows
#define NRP   1920      // padded to 30*64 tiles
#define CH    256       // channels
#define CAP   3072      // max keys kept per (image,class) list (mean ~1724, sd ~41)

// ---- workspace layout (FLOAT units) ----
#define OFF_LD   65536u    // int   [2][HW]                     65536
#define OFF_SEL  131072u   // int   [NT*VIEWS]=1900 (pad 2048)
#define OFF_CNT  133120u   // int   [NT] (pad 64)
#define OFF_KEYS 133184u   // ull   [NT][CAP] = 233472 floats (8B-aligned)
#define OFF_FCF  366656u   // ushort[NRP][CH] = 245760 floats
#define OFF_FOF  612416u   // ushort[NRP][CH] = 245760 floats
#define OFF_NEG  858176u   // float [3][NR] = 5700 (pad 5760)
#define OFF_POS  863936u   // float [3][NR][100] = 570000
// end 1433936 floats = 5.74 MB

typedef __attribute__((ext_vector_type(8))) short short8;
typedef __attribute__((ext_vector_type(4))) float f32x4;

__device__ __forceinline__ unsigned rotl32(unsigned x, int d) {
    return (x << d) | (x >> (32 - d));
}

__device__ __forceinline__ void async_copy16(const void* g, void* l) {
    __builtin_amdgcn_global_load_lds(
        (const __attribute__((address_space(1))) unsigned int*)g,
        (__attribute__((address_space(3))) unsigned int*)l, 16, 0, 0);
}

// Kernel 1: threefry2x32 uniforms (key 42) + label downsample + per-(n,c) key
// compaction into global lists + negsum/out zeroing. rnd is never materialized.
__global__ __launch_bounds__(256) void prep_kernel(const int* __restrict__ label,
                                                   int* __restrict__ ld,
                                                   int* __restrict__ counts,
                                                   unsigned long long* __restrict__ keys,
                                                   float* __restrict__ negsum,
                                                   float* __restrict__ out) {
    int tid = threadIdx.x;
    int j = blockIdx.x * 256 + tid;
    unsigned x0 = (unsigned)j, x1 = (unsigned)(j + HW);
    const unsigned ks0 = 0u, ks1 = 42u, ks2 = 0x1BD11BDAu ^ 0u ^ 42u;
    x0 += ks0; x1 += ks1;
#define TF_RND(r) { x0 += x1; x1 = rotl32(x1, r); x1 ^= x0; }
    TF_RND(13) TF_RND(15) TF_RND(26) TF_RND(6)   x0 += ks1; x1 += ks2 + 1u;
    TF_RND(17) TF_RND(29) TF_RND(16) TF_RND(24)  x0 += ks2; x1 += ks0 + 2u;
    TF_RND(13) TF_RND(15) TF_RND(26) TF_RND(6)   x0 += ks0; x1 += ks1 + 3u;
    TF_RND(17) TF_RND(29) TF_RND(16) TF_RND(24)  x0 += ks1; x1 += ks2 + 4u;
    TF_RND(13) TF_RND(15) TF_RND(26) TF_RND(6)   x0 += ks2; x1 += ks0 + 5u;
#undef TF_RND
    float r0 = __uint_as_float((x0 >> 9) | 0x3f800000u) - 1.0f;
    float r1 = __uint_as_float((x1 >> 9) | 0x3f800000u) - 1.0f;
    int y = j >> 8, x = j & 255;
    int off = (y << 2) * 1024 + (x << 2);
    int c0 = label[off];
    int c1 = label[512 * 1024 + off];
    ld[j]      = c0;
    ld[HW + j] = c1;
    if (j < 3 * NR) negsum[j] = 0.0f;
    if (j < 3) out[j] = 0.0f;

    // block-aggregated push into per-(n,c) lists
    __shared__ int lcnt[NT], lbase[NT];
    if (tid < NT) lcnt[tid] = 0;
    __syncthreads();
    int t0 = c0, t1 = NCLS + c1;
    int p0 = atomicAdd(&lcnt[t0], 1);
    int p1 = atomicAdd(&lcnt[t1], 1);
    __syncthreads();
    if (tid < NT) {
        int c = lcnt[tid];
        lbase[tid] = (c > 0) ? atomicAdd(&counts[tid], c) : 0;
    }
    __syncthreads();
    int s0 = lbase[t0] + p0;
    int s1 = lbase[t1] + p1;
    if (s0 < CAP)
        keys[(size_t)t0 * CAP + s0] = (((unsigned long long)__float_as_uint(r0)) << 32) | (unsigned)j;
    if (s1 < CAP)
        keys[(size_t)t1 * CAP + s1] = (((unsigned long long)__float_as_uint(r1)) << 32) | (unsigned)j;
}

// Kernel 2: exact order-free top-50 per (image,class) via 256-bin histogram select.
__global__ __launch_bounds__(256) void select_kernel(const int* __restrict__ counts,
                                                     const unsigned long long* __restrict__ keys,
                                                     const int* __restrict__ ld,
                                                     int* __restrict__ sel) {
    int t = blockIdx.x;
    int tid = threadIdx.x;
    int cnt = min(counts[t], CAP);
    const unsigned long long* g = keys + (size_t)t * CAP;
    __shared__ unsigned hist[256];
    __shared__ unsigned long long cand[256];
    __shared__ int s_B, s_nbelow, s_ncand;
    hist[tid] = 0;
    if (tid == 0) { s_B = 256; s_nbelow = 0; s_ncand = 0; }
    __syncthreads();

    unsigned long long kreg[12];
    int binreg[12];
    int nk = 0;
    for (int p = tid; p < cnt; p += 256) {
        unsigned long long k = g[p];
        unsigned v = (unsigned)(__uint_as_float((unsigned)(k >> 32)) * 8388608.0f);
        int b = (int)(v >> 15);
        kreg[nk] = k; binreg[nk] = b; nk++;
        atomicAdd(&hist[b], 1u);
    }
    __syncthreads();

    if (cnt >= VIEWS) {
        for (int s = 1; s < 256; s <<= 1) {
            unsigned add = (tid >= s) ? hist[tid - s] : 0u;
            unsigned cur = hist[tid];
            __syncthreads();
            hist[tid] = cur + add;
            __syncthreads();
        }
        unsigned cum  = hist[tid];
        unsigned prev = (tid > 0) ? hist[tid - 1] : 0u;
        if (cum >= VIEWS && prev < VIEWS) s_B = tid;
        __syncthreads();
        int B = s_B;
        for (int q = 0; q < nk; ++q) {
            if (binreg[q] < B) {
                int pos = atomicAdd(&s_nbelow, 1);
                if (pos < VIEWS) sel[t * VIEWS + pos] = (int)(kreg[q] & 0xffffffffu);
            } else if (binreg[q] == B) {
                int pos = atomicAdd(&s_ncand, 1);
                if (pos < 256) cand[pos] = kreg[q];
            }
        }
        __syncthreads();
        int nbelow = s_nbelow;
        int need   = VIEWS - nbelow;
        int ncand  = min(s_ncand, 256);
        if (tid < 64) {
            unsigned long long r0 = (tid       < ncand) ? cand[tid]       : ~0ull;
            unsigned long long r1 = (tid + 64  < ncand) ? cand[tid + 64]  : ~0ull;
            unsigned long long r2 = (tid + 128 < ncand) ? cand[tid + 128] : ~0ull;
            unsigned long long r3 = (tid + 192 < ncand) ? cand[tid + 192] : ~0ull;
            for (int v = 0; v < need; ++v) {
                unsigned long long a = (r0 < r1) ? r0 : r1;
                unsigned long long b = (r2 < r3) ? r2 : r3;
                unsigned long long best = (a < b) ? a : b;
                for (int m = 32; m >= 1; m >>= 1) {
                    unsigned long long o = __shfl_xor(best, m);
                    if (o < best) best = o;
                }
                if (tid == 0) sel[t * VIEWS + nbelow + v] = (int)(best & 0xffffffffu);
                if (r0 == best) r0 = ~0ull;
                if (r1 == best) r1 = ~0ull;
                if (r2 == best) r2 = ~0ull;
                if (r3 == best) r3 = ~0ull;
            }
        }
    } else {
        for (int q = 0; q < nk; ++q) {
            int pos = atomicAdd(&s_nbelow, 1);
            if (pos < VIEWS) sel[t * VIEWS + pos] = (int)(kreg[q] & 0xffffffffu);
        }
        __syncthreads();
        if (tid == 0) {
            int fill = s_nbelow;
            int n = t / NCLS, c = t % NCLS;
            const int* ldn = ld + n * HW;
            for (int j = 0; j < HW && fill < VIEWS; ++j)
                if (ldn[j] != c) sel[t * VIEWS + fill++] = j;
        }
    }
}

// Kernel 3: gather sampled pixels, l2-normalize, store bf16 bits; pad rows zeroed.
__global__ __launch_bounds__(256) void gather_kernel(const float* __restrict__ cf,
                                                     const float* __restrict__ of,
                                                     const int* __restrict__ sel,
                                                     unsigned short* __restrict__ fcf,
                                                     unsigned short* __restrict__ fof) {
    int r = blockIdx.x;              // 0..NRP-1
    int ch = threadIdx.x;
    if (r >= NR) {
        fcf[r * CH + ch] = 0;
        fof[r * CH + ch] = 0;
        return;
    }
    int t = r / VIEWS;
    int n = t / NCLS;
    int idx = sel[r];
    float vc = cf[(size_t)(n * CH + ch) * HW + idx];
    float vo = of[(size_t)(n * CH + ch) * HW + idx];
    __shared__ float partc[4], parto[4];
    float sc = vc * vc, so = vo * vo;
    for (int m = 32; m >= 1; m >>= 1) {
        sc += __shfl_xor(sc, m);
        so += __shfl_xor(so, m);
    }
    int wave = ch >> 6, lane = ch & 63;
    if (lane == 0) { partc[wave] = sc; parto[wave] = so; }
    __syncthreads();
    float nc = fmaxf(sqrtf(partc[0] + partc[1] + partc[2] + partc[3]), 1e-12f);
    float no = fmaxf(sqrtf(parto[0] + parto[1] + parto[2] + parto[3]), 1e-12f);
    __hip_bfloat16 hc = __float2bfloat16(vc / nc);
    __hip_bfloat16 ho = __float2bfloat16(vo / no);
    fcf[r * CH + ch] = *(unsigned short*)&hc;
    fof[r * CH + ch] = *(unsigned short*)&ho;
}

// Kernel 4: bf16 MFMA Gram (A.B^T * 10) with fused InfoNCE epilogue.
// z=0: cm (fcf,fof) full; z=1: vis (fcf,fcf) and z=2: aux (fof,fof) are symmetric:
// only tiles i0<=j0 computed, strict-upper tiles mirror their epilogue (pd transpose
// write + column exp-sums into negsum[j]). Each (i,j) pair handled exactly once.
__global__ __launch_bounds__(256) void gram_kernel(const unsigned short* __restrict__ fcf,
                                                   const unsigned short* __restrict__ fof,
                                                   float* __restrict__ negsum,
                                                   float* __restrict__ posdot) {
    int z = blockIdx.z;
    bool sym = (z >= 1);
    if (sym && blockIdx.y > blockIdx.x) return;     // lower-triangle tiles skipped
    bool mirror = sym && (blockIdx.y < blockIdx.x);
    const unsigned short* A = (z == 2) ? fof : fcf;
    const unsigned short* B = (z == 1) ? fcf : fof;
    int i0 = blockIdx.y * 64, j0 = blockIdx.x * 64;
    int tid = threadIdx.x;
    int wave = tid >> 6, lane = tid & 63;
    __shared__ unsigned short As[64][32], Bs[64][32];
    __shared__ float negs[64], negsB[64];
    if (tid < 64) { negs[tid] = 0.0f; negsB[tid] = 0.0f; }
    f32x4 acc[4] = {{0,0,0,0},{0,0,0,0},{0,0,0,0},{0,0,0,0}};
    int srow = wave * 16 + (lane >> 2);
    int scol = (lane & 3) * 8;
    const unsigned short* ga = A + (size_t)(i0 + srow) * CH + scol;
    const unsigned short* gb = B + (size_t)(j0 + srow) * CH + scol;
    unsigned short* la = &As[wave * 16][0];
    unsigned short* lb = &Bs[wave * 16][0];
    int arow = wave * 16 + (lane & 15);
    int koff = (lane >> 4) * 8;
    for (int kc = 0; kc < CH; kc += 32) {
        async_copy16(ga + kc, la);
        async_copy16(gb + kc, lb);
        __syncthreads();
        short8 af = *(const short8*)&As[arow][koff];
        for (int b = 0; b < 4; ++b) {
            short8 bf = *(const short8*)&Bs[b * 16 + (lane & 15)][koff];
            acc[b] = __builtin_amdgcn_mfma_f32_16x16x32_bf16(af, bf, acc[b], 0, 0, 0);
        }
        __syncthreads();
    }
    // epilogue: C/D layout col=lane&15, row=(lane>>4)*4+reg (wave's rows: +wave*16)
    float* pd = posdot + (size_t)z * NR * 100;
    int col = lane & 15, quad = lane >> 4;
    float negB[4] = {0.0f, 0.0f, 0.0f, 0.0f};
    for (int r = 0; r < 4; ++r) {
        int irow = wave * 16 + quad * 4 + r;
        int i = i0 + irow;
        bool iok = (i < NR);
        int ci = (i / VIEWS) % NCLS;
        float negacc = 0.0f;
        for (int b = 0; b < 4; ++b) {
            int j = j0 + b * 16 + col;
            if (!iok || j >= NR) continue;
            int cj = (j / VIEWS) % NCLS;
            float d = acc[b][r] * 10.0f;   // 1/temp
            if (ci == cj) {
                int p = (j / (NCLS * VIEWS)) * VIEWS + (j % VIEWS);
                pd[(size_t)i * 100 + p] = d;
                if (mirror) {
                    int q = (i / (NCLS * VIEWS)) * VIEWS + (i % VIEWS);
                    pd[(size_t)j * 100 + q] = d;
                }
            } else {
                float e = __expf(d);
                negacc += e;
                if (mirror) negB[b] += e;
            }
        }
        for (int m = 8; m >= 1; m >>= 1) negacc += __shfl_xor(negacc, m);
        if (col == 0 && iok) negs[irow] = negacc;
    }
    if (mirror) {
        for (int b = 0; b < 4; ++b) {
            float v = negB[b];
            v += __shfl_xor(v, 16);
            v += __shfl_xor(v, 32);
            if (quad == 0) atomicAdd(&negsB[b * 16 + col], v);
        }
    }
    __syncthreads();
    if (tid < 64) {
        int i = i0 + tid;
        if (i < NR) atomicAdd(&negsum[z * NR + i], negs[tid]);
        if (mirror) {
            int j = j0 + tid;
            if (j < NR) atomicAdd(&negsum[z * NR + j], negsB[tid]);
        }
    }
}

// Kernel 5: per-anchor InfoNCE from stored same-class dots + neg exp sums.
__global__ void finalize_kernel(const float* __restrict__ negsum,
                                const float* __restrict__ posdot,
                                float* __restrict__ out) {
    int g = blockIdx.x * 256 + threadIdx.x;
    __shared__ float part[3];
    if (threadIdx.x < 3) part[threadIdx.x] = 0.0f;
    __syncthreads();
    if (g < 3 * NR) {
        int l = g / NR, i = g % NR;
        float NL = negsum[l * NR + i];
        int pself = (i / (NCLS * VIEWS)) * VIEWS + (i % VIEWS);
        const float* pd = posdot + ((size_t)l * NR + i) * 100;
        float s = 0.0f;
        for (int p = 0; p < 100; ++p) {
            if (p == pself) continue;
            float d = pd[p];
            s += d - logf(__expf(d) + NL);
        }
        atomicAdd(&part[l], s);
    }
    __syncthreads();
    if (threadIdx.x < 3)
        atomicAdd(&out[threadIdx.x], -part[threadIdx.x] * (1.0f / (99.0f * 1900.0f)));
}

extern "C" void kernel_launch(void* const* d_in, const int* in_sizes, int n_in,
                              void* d_out, int out_size, void* d_ws, size_t ws_size,
                              hipStream_t stream) {
    (void)in_sizes; (void)n_in; (void)out_size; (void)ws_size;
    const int*   label = (const int*)d_in[0];
    const float* cf    = (const float*)d_in[1];
    const float* of    = (const float*)d_in[2];
    float* ws = (float*)d_ws;
    int*                ld     = (int*)(ws + OFF_LD);
    int*                sel    = (int*)(ws + OFF_SEL);
    int*                counts = (int*)(ws + OFF_CNT);
    unsigned long long* keys   = (unsigned long long*)(ws + OFF_KEYS);
    unsigned short*     fcf    = (unsigned short*)(ws + OFF_FCF);
    unsigned short*     fof    = (unsigned short*)(ws + OFF_FOF);
    float*              negsum = ws + OFF_NEG;
    float*              posdot = ws + OFF_POS;
    float*              out    = (float*)d_out;

    hipMemsetAsync(counts, 0, NT * sizeof(int), stream);

    prep_kernel<<<HW / 256, 256, 0, stream>>>(label, ld, counts, keys, negsum, out);
    select_kernel<<<NT, 256, 0, stream>>>(counts, keys, ld, sel);
    gather_kernel<<<NRP, 256, 0, stream>>>(cf, of, sel, fcf, fof);
    dim3 g4(NRP / 64, NRP / 64, 3);
    gram_kernel<<<g4, 256, 0, stream>>>(fcf, fof, negsum, posdot);
    finalize_kernel<<<(3 * NR + 255) / 256, 256, 0, stream>>>(negsum, posdot, out);
}

// Round 6
// 204.348 us; speedup vs baseline: 2.3763x; 1.0030x over previous
//
#include <hip/hip_runtime.h>
#include <hip/hip_bf16.h>
#include <cstdint>
#include <cstddef>

#define HW    32768     // 128*256 feature pixels per image
#define NCLS  19
#define VIEWS 50
#define NT    38        // 2 images * 19 classes
#define NR    1900      // NT * VIEWS anchor rows
#define NRP   1920      // padded to 30*64 tiles
#define CH    256       // channels
#define CAP   3072      // max keys kept per (image,class) list (mean ~1724, sd ~41)

// ---- workspace layout (FLOAT units) ----
#define OFF_LD   65536u    // int   [2][HW]                     65536
#define OFF_SEL  131072u   // int   [NT*VIEWS]=1900 (pad 2048)
#define OFF_CNT  133120u   // int   [NT] (pad 64)
#define OFF_KEYS 133184u   // ull   [NT][CAP] = 233472 floats (8B-aligned)
#define OFF_FCF  366656u   // ushort[NRP][CH] = 245760 floats
#define OFF_FOF  612416u   // ushort[NRP][CH] = 245760 floats
#define OFF_NEG  858176u   // float [3][NR] = 5700 (pad 5760)
#define OFF_POS  863936u   // float [3][NR][100] = 570000
// end 1433936 floats = 5.74 MB

typedef __attribute__((ext_vector_type(8))) short short8;
typedef __attribute__((ext_vector_type(4))) float f32x4;

__device__ __forceinline__ unsigned rotl32(unsigned x, int d) {
    return (x << d) | (x >> (32 - d));
}

// Kernel 1: threefry2x32 uniforms (key 42) + label downsample + per-(n,c) key
// compaction into global lists + negsum/out zeroing. rnd is never materialized.
__global__ __launch_bounds__(256) void prep_kernel(const int* __restrict__ label,
                                                   int* __restrict__ ld,
                                                   int* __restrict__ counts,
                                                   unsigned long long* __restrict__ keys,
                                                   float* __restrict__ negsum,
                                                   float* __restrict__ out) {
    int tid = threadIdx.x;
    int j = blockIdx.x * 256 + tid;
    unsigned x0 = (unsigned)j, x1 = (unsigned)(j + HW);
    const unsigned ks0 = 0u, ks1 = 42u, ks2 = 0x1BD11BDAu ^ 0u ^ 42u;
    x0 += ks0; x1 += ks1;
#define TF_RND(r) { x0 += x1; x1 = rotl32(x1, r); x1 ^= x0; }
    TF_RND(13) TF_RND(15) TF_RND(26) TF_RND(6)   x0 += ks1; x1 += ks2 + 1u;
    TF_RND(17) TF_RND(29) TF_RND(16) TF_RND(24)  x0 += ks2; x1 += ks0 + 2u;
    TF_RND(13) TF_RND(15) TF_RND(26) TF_RND(6)   x0 += ks0; x1 += ks1 + 3u;
    TF_RND(17) TF_RND(29) TF_RND(16) TF_RND(24)  x0 += ks1; x1 += ks2 + 4u;
    TF_RND(13) TF_RND(15) TF_RND(26) TF_RND(6)   x0 += ks2; x1 += ks0 + 5u;
#undef TF_RND
    float r0 = __uint_as_float((x0 >> 9) | 0x3f800000u) - 1.0f;
    float r1 = __uint_as_float((x1 >> 9) | 0x3f800000u) - 1.0f;
    int y = j >> 8, x = j & 255;
    int off = (y << 2) * 1024 + (x << 2);
    int c0 = label[off];
    int c1 = label[512 * 1024 + off];
    ld[j]      = c0;
    ld[HW + j] = c1;
    if (j < 3 * NR) negsum[j] = 0.0f;
    if (j < 3) out[j] = 0.0f;

    // block-aggregated push into per-(n,c) lists
    __shared__ int lcnt[NT], lbase[NT];
    if (tid < NT) lcnt[tid] = 0;
    __syncthreads();
    int t0 = c0, t1 = NCLS + c1;
    int p0 = atomicAdd(&lcnt[t0], 1);
    int p1 = atomicAdd(&lcnt[t1], 1);
    __syncthreads();
    if (tid < NT) {
        int c = lcnt[tid];
        lbase[tid] = (c > 0) ? atomicAdd(&counts[tid], c) : 0;
    }
    __syncthreads();
    int s0 = lbase[t0] + p0;
    int s1 = lbase[t1] + p1;
    if (s0 < CAP)
        keys[(size_t)t0 * CAP + s0] = (((unsigned long long)__float_as_uint(r0)) << 32) | (unsigned)j;
    if (s1 < CAP)
        keys[(size_t)t1 * CAP + s1] = (((unsigned long long)__float_as_uint(r1)) << 32) | (unsigned)j;
}

// Kernel 2: exact order-free top-50 per (image,class) via 256-bin histogram select.
__global__ __launch_bounds__(256) void select_kernel(const int* __restrict__ counts,
                                                     const unsigned long long* __restrict__ keys,
                                                     const int* __restrict__ ld,
                                                     int* __restrict__ sel) {
    int t = blockIdx.x;
    int tid = threadIdx.x;
    int cnt = min(counts[t], CAP);
    const unsigned long long* g = keys + (size_t)t * CAP;
    __shared__ unsigned hist[256];
    __shared__ unsigned long long cand[256];
    __shared__ int s_B, s_nbelow, s_ncand;
    hist[tid] = 0;
    if (tid == 0) { s_B = 256; s_nbelow = 0; s_ncand = 0; }
    __syncthreads();

    unsigned long long kreg[12];
    int binreg[12];
    int nk = 0;
    for (int p = tid; p < cnt; p += 256) {
        unsigned long long k = g[p];
        unsigned v = (unsigned)(__uint_as_float((unsigned)(k >> 32)) * 8388608.0f);
        int b = (int)(v >> 15);
        kreg[nk] = k; binreg[nk] = b; nk++;
        atomicAdd(&hist[b], 1u);
    }
    __syncthreads();

    if (cnt >= VIEWS) {
        for (int s = 1; s < 256; s <<= 1) {
            unsigned add = (tid >= s) ? hist[tid - s] : 0u;
            unsigned cur = hist[tid];
            __syncthreads();
            hist[tid] = cur + add;
            __syncthreads();
        }
        unsigned cum  = hist[tid];
        unsigned prev = (tid > 0) ? hist[tid - 1] : 0u;
        if (cum >= VIEWS && prev < VIEWS) s_B = tid;
        __syncthreads();
        int B = s_B;
        for (int q = 0; q < nk; ++q) {
            if (binreg[q] < B) {
                int pos = atomicAdd(&s_nbelow, 1);
                if (pos < VIEWS) sel[t * VIEWS + pos] = (int)(kreg[q] & 0xffffffffu);
            } else if (binreg[q] == B) {
                int pos = atomicAdd(&s_ncand, 1);
                if (pos < 256) cand[pos] = kreg[q];
            }
        }
        __syncthreads();
        int nbelow = s_nbelow;
        int need   = VIEWS - nbelow;
        int ncand  = min(s_ncand, 256);
        if (tid < 64) {
            unsigned long long r0 = (tid       < ncand) ? cand[tid]       : ~0ull;
            unsigned long long r1 = (tid + 64  < ncand) ? cand[tid + 64]  : ~0ull;
            unsigned long long r2 = (tid + 128 < ncand) ? cand[tid + 128] : ~0ull;
            unsigned long long r3 = (tid + 192 < ncand) ? cand[tid + 192] : ~0ull;
            for (int v = 0; v < need; ++v) {
                unsigned long long a = (r0 < r1) ? r0 : r1;
                unsigned long long b = (r2 < r3) ? r2 : r3;
                unsigned long long best = (a < b) ? a : b;
                for (int m = 32; m >= 1; m >>= 1) {
                    unsigned long long o = __shfl_xor(best, m);
                    if (o < best) best = o;
                }
                if (tid == 0) sel[t * VIEWS + nbelow + v] = (int)(best & 0xffffffffu);
                if (r0 == best) r0 = ~0ull;
                if (r1 == best) r1 = ~0ull;
                if (r2 == best) r2 = ~0ull;
                if (r3 == best) r3 = ~0ull;
            }
        }
    } else {
        for (int q = 0; q < nk; ++q) {
            int pos = atomicAdd(&s_nbelow, 1);
            if (pos < VIEWS) sel[t * VIEWS + pos] = (int)(kreg[q] & 0xffffffffu);
        }
        __syncthreads();
        if (tid == 0) {
            int fill = s_nbelow;
            int n = t / NCLS, c = t % NCLS;
            const int* ldn = ld + n * HW;
            for (int j = 0; j < HW && fill < VIEWS; ++j)
                if (ldn[j] != c) sel[t * VIEWS + fill++] = j;
        }
    }
}

// Kernel 3: gather sampled pixels, l2-normalize, store bf16 bits; pad rows zeroed.
__global__ __launch_bounds__(256) void gather_kernel(const float* __restrict__ cf,
                                                     const float* __restrict__ of,
                                                     const int* __restrict__ sel,
                                                     unsigned short* __restrict__ fcf,
                                                     unsigned short* __restrict__ fof) {
    int r = blockIdx.x;              // 0..NRP-1
    int ch = threadIdx.x;
    if (r >= NR) {
        fcf[r * CH + ch] = 0;
        fof[r * CH + ch] = 0;
        return;
    }
    int t = r / VIEWS;
    int n = t / NCLS;
    int idx = sel[r];
    float vc = cf[(size_t)(n * CH + ch) * HW + idx];
    float vo = of[(size_t)(n * CH + ch) * HW + idx];
    __shared__ float partc[4], parto[4];
    float sc = vc * vc, so = vo * vo;
    for (int m = 32; m >= 1; m >>= 1) {
        sc += __shfl_xor(sc, m);
        so += __shfl_xor(so, m);
    }
    int wave = ch >> 6, lane = ch & 63;
    if (lane == 0) { partc[wave] = sc; parto[wave] = so; }
    __syncthreads();
    float nc = fmaxf(sqrtf(partc[0] + partc[1] + partc[2] + partc[3]), 1e-12f);
    float no = fmaxf(sqrtf(parto[0] + parto[1] + parto[2] + parto[3]), 1e-12f);
    __hip_bfloat16 hc = __float2bfloat16(vc / nc);
    __hip_bfloat16 ho = __float2bfloat16(vo / no);
    fcf[r * CH + ch] = *(unsigned short*)&hc;
    fof[r * CH + ch] = *(unsigned short*)&ho;
}

// Kernel 4: bf16 MFMA Gram (A.B^T * 10) with fused InfoNCE epilogue.
// One-shot K: A-fragments direct global->VGPR; B-tile staged once to LDS
// (row stride 272 ushort = even 4-bank-span distribution for b128 reads);
// a single barrier, then 32 MFMAs. z=0: cm (fcf,fof) full; z=1 vis / z=2 aux
// symmetric: tiles i0<=j0 only, strict-upper mirrors the epilogue.
#define BLDS 272
__global__ __launch_bounds__(256) void gram_kernel(const unsigned short* __restrict__ fcf,
                                                   const unsigned short* __restrict__ fof,
                                                   float* __restrict__ negsum,
                                                   float* __restrict__ posdot) {
    int z = blockIdx.z;
    bool sym = (z >= 1);
    if (sym && blockIdx.y > blockIdx.x) return;     // lower-triangle tiles skipped
    bool mirror = sym && (blockIdx.y < blockIdx.x);
    const unsigned short* A = (z == 2) ? fof : fcf;
    const unsigned short* B = (z == 1) ? fcf : fof;
    int i0 = blockIdx.y * 64, j0 = blockIdx.x * 64;
    int tid = threadIdx.x;
    int wave = tid >> 6, lane = tid & 63;
    __shared__ unsigned short Bs[64][BLDS];
    __shared__ float negs[64], negsB[64];
    if (tid < 64) { negs[tid] = 0.0f; negsB[tid] = 0.0f; }

    // B tile -> registers (8 x dwordx4, coalesced)
    short8 breg[8];
#pragma unroll
    for (int m = 0; m < 8; ++m) {
        int e = m * 256 + tid;                 // 0..2047
        int row = e >> 5, ch = (e & 31) * 8;
        breg[m] = *(const short8*)(B + (size_t)(j0 + row) * CH + ch);
    }
    // A fragments direct to VGPR: lane owns row wave*16+(lane&15), chunks k*4+(lane>>4)
    const unsigned short* pa = A + (size_t)(i0 + wave * 16 + (lane & 15)) * CH + (lane >> 4) * 8;
    short8 af[8];
#pragma unroll
    for (int k = 0; k < 8; ++k) af[k] = *(const short8*)(pa + k * 32);
    // registers -> LDS
#pragma unroll
    for (int m = 0; m < 8; ++m) {
        int e = m * 256 + tid;
        int row = e >> 5, ch = (e & 31) * 8;
        *(short8*)&Bs[row][ch] = breg[m];
    }
    __syncthreads();

    f32x4 acc[4] = {{0,0,0,0},{0,0,0,0},{0,0,0,0},{0,0,0,0}};
#pragma unroll
    for (int k = 0; k < 8; ++k) {
#pragma unroll
        for (int b = 0; b < 4; ++b) {
            short8 bf = *(const short8*)&Bs[b * 16 + (lane & 15)][k * 32 + (lane >> 4) * 8];
            acc[b] = __builtin_amdgcn_mfma_f32_16x16x32_bf16(af[k], bf, acc[b], 0, 0, 0);
        }
    }

    // epilogue: C/D layout col=lane&15, row=(lane>>4)*4+reg (wave's rows: +wave*16)
    float* pd = posdot + (size_t)z * NR * 100;
    int col = lane & 15, quad = lane >> 4;
    float negB[4] = {0.0f, 0.0f, 0.0f, 0.0f};
    for (int r = 0; r < 4; ++r) {
        int irow = wave * 16 + quad * 4 + r;
        int i = i0 + irow;
        bool iok = (i < NR);
        int ci = (i / VIEWS) % NCLS;
        float negacc = 0.0f;
        for (int b = 0; b < 4; ++b) {
            int j = j0 + b * 16 + col;
            if (!iok || j >= NR) continue;
            int cj = (j / VIEWS) % NCLS;
            float d = acc[b][r] * 10.0f;   // 1/temp
            if (ci == cj) {
                int p = (j / (NCLS * VIEWS)) * VIEWS + (j % VIEWS);
                pd[(size_t)i * 100 + p] = d;
                if (mirror) {
                    int q = (i / (NCLS * VIEWS)) * VIEWS + (i % VIEWS);
                    pd[(size_t)j * 100 + q] = d;
                }
            } else {
                float e = __expf(d);
                negacc += e;
                if (mirror) negB[b] += e;
            }
        }
        for (int m = 8; m >= 1; m >>= 1) negacc += __shfl_xor(negacc, m);
        if (col == 0 && iok) negs[irow] = negacc;
    }
    if (mirror) {
        for (int b = 0; b < 4; ++b) {
            float v = negB[b];
            v += __shfl_xor(v, 16);
            v += __shfl_xor(v, 32);
            if (quad == 0) atomicAdd(&negsB[b * 16 + col], v);
        }
    }
    __syncthreads();
    if (tid < 64) {
        int i = i0 + tid;
        if (i < NR) atomicAdd(&negsum[z * NR + i], negs[tid]);
        if (mirror) {
            int j = j0 + tid;
            if (j < NR) atomicAdd(&negsum[z * NR + j], negsB[tid]);
        }
    }
}

// Kernel 5: per-anchor InfoNCE from stored same-class dots + neg exp sums.
__global__ void finalize_kernel(const float* __restrict__ negsum,
                                const float* __restrict__ posdot,
                                float* __restrict__ out) {
    int g = blockIdx.x * 256 + threadIdx.x;
    __shared__ float part[3];
    if (threadIdx.x < 3) part[threadIdx.x] = 0.0f;
    __syncthreads();
    if (g < 3 * NR) {
        int l = g / NR, i = g % NR;
        float NL = negsum[l * NR + i];
        int pself = (i / (NCLS * VIEWS)) * VIEWS + (i % VIEWS);
        const float* pd = posdot + ((size_t)l * NR + i) * 100;
        float s = 0.0f;
        for (int p = 0; p < 100; ++p) {
            if (p == pself) continue;
            float d = pd[p];
            s += d - logf(__expf(d) + NL);
        }
        atomicAdd(&part[l], s);
    }
    __syncthreads();
    if (threadIdx.x < 3)
        atomicAdd(&out[threadIdx.x], -part[threadIdx.x] * (1.0f / (99.0f * 1900.0f)));
}

extern "C" void kernel_launch(void* const* d_in, const int* in_sizes, int n_in,
                              void* d_out, int out_size, void* d_ws, size_t ws_size,
                              hipStream_t stream) {
    (void)in_sizes; (void)n_in; (void)out_size; (void)ws_size;
    const int*   label = (const int*)d_in[0];
    const float* cf    = (const float*)d_in[1];
    const float* of    = (const float*)d_in[2];
    float* ws = (float*)d_ws;
    int*                ld     = (int*)(ws + OFF_LD);
    int*                sel    = (int*)(ws + OFF_SEL);
    int*                counts = (int*)(ws + OFF_CNT);
    unsigned long long* keys   = (unsigned long long*)(ws + OFF_KEYS);
    unsigned short*     fcf    = (unsigned short*)(ws + OFF_FCF);
    unsigned short*     fof    = (unsigned short*)(ws + OFF_FOF);
    float*              negsum = ws + OFF_NEG;
    float*              posdot = ws + OFF_POS;
    float*              out    = (float*)d_out;

    hipMemsetAsync(counts, 0, NT * sizeof(int), stream);

    prep_kernel<<<HW / 256, 256, 0, stream>>>(label, ld, counts, keys, negsum, out);
    select_kernel<<<NT, 256, 0, stream>>>(counts, keys, ld, sel);
    gather_kernel<<<NRP, 256, 0, stream>>>(cf, of, sel, fcf, fof);
    dim3 g4(NRP / 64, NRP / 64, 3);
    gram_kernel<<<g4, 256, 0, stream>>>(fcf, fof, negsum, posdot);
    finalize_kernel<<<(3 * NR + 255) / 256, 256, 0, stream>>>(negsum, posdot, out);
}